// Round 1
// baseline (151.748 us; speedup 1.0000x reference)
//
#include <hip/hip_runtime.h>

#define GAMMA 0.99f
#define T_DIM 128
#define B_DIM 512
#define Q_DIM 50

// ---------------------------------------------------------------------------
// K1: backward scan over t. One thread per (b,q) chain; idx = b*Q + q, so
// target_value[t*BQ + idx] is fully coalesced. rets has T-1 rows.
// ---------------------------------------------------------------------------
__global__ void __launch_bounds__(256) scan_kernel(
    const float* __restrict__ reward,
    const int*   __restrict__ step_type,
    const float* __restrict__ discount,
    const float* __restrict__ target_value,
    float*       __restrict__ rets) {
  const int idx = blockIdx.x * blockDim.x + threadIdx.x;   // b*Q + q
  if (idx >= B_DIM * Q_DIM) return;
  const int b  = idx / Q_DIM;
  const int BQ = B_DIM * Q_DIM;

  float carry = target_value[(T_DIM - 1) * BQ + idx];
  for (int t = T_DIM - 2; t >= 0; --t) {
    const float d   = discount[(t + 1) * B_DIM + b] * GAMMA;
    const float r   = reward[(t + 1) * B_DIM + b];
    const float acc = fmaf(carry, d, r);
    const float v   = target_value[t * BQ + idx];
    const bool last = (step_type[t * B_DIM + b] == 2);
    const float ret = last ? v : acc;
    rets[t * BQ + idx] = ret;
    carry = ret;
  }
}

// ---------------------------------------------------------------------------
// K2: quantile huber loss. One wave per (t,b). Lane j holds v_j, ret_j, tau_j.
// Inner loop broadcasts ret_i via readlane (SGPR, free as VALU operand).
//   loss[t,b] = (1/Q) * sum_j sum_i |tau_j - (diff<0)| * huber(diff),
//   diff = ret_i - v_j
// Row t = T-1 of out is zeroed here (harness poisons d_out).
// ---------------------------------------------------------------------------
__global__ void __launch_bounds__(256) loss_kernel(
    const float* __restrict__ value,
    const float* __restrict__ rets,
    float*       __restrict__ out) {
  const int wid  = blockIdx.x * (blockDim.x >> 6) + (threadIdx.x >> 6);
  const int lane = threadIdx.x & 63;
  const int t = wid >> 9;          // / B_DIM
  const int b = wid & (B_DIM - 1);

  if (t >= T_DIM - 1) {            // last row: loss is defined as zero
    if (lane == 0) out[t * B_DIM + b] = 0.0f;
    return;
  }

  const float* vp = value + (t * B_DIM + b) * Q_DIM;
  const float* rp = rets  + (t * B_DIM + b) * Q_DIM;

  float v = 0.0f, ret = 0.0f;
  if (lane < Q_DIM) {
    v   = vp[lane];
    ret = rp[lane];
  }
  const float tau   = ((float)lane + 0.5f) * (1.0f / Q_DIM);
  const float omtau = 1.0f - tau;

  float s = 0.0f;
#pragma unroll 10
  for (int i = 0; i < Q_DIM; ++i) {
    const float reti = __int_as_float(
        __builtin_amdgcn_readlane(__float_as_int(ret), i));
    const float diff = reti - v;
    const float w    = (diff < 0.0f) ? omtau : tau;    // |tau - (diff<0)|
    const float ad   = fabsf(diff);
    const float m    = fminf(ad, 1.0f);
    const float h    = m * fmaf(-0.5f, m, ad);         // huber(diff)
    s = fmaf(w, h, s);
  }
  if (lane >= Q_DIM) s = 0.0f;     // lanes 50..63 computed garbage

  // wave reduction (64 lanes)
#pragma unroll
  for (int off = 32; off > 0; off >>= 1)
    s += __shfl_down(s, off, 64);

  if (lane == 0) out[t * B_DIM + b] = s * (1.0f / Q_DIM);
}

// ---------------------------------------------------------------------------
extern "C" void kernel_launch(void* const* d_in, const int* in_sizes, int n_in,
                              void* d_out, int out_size, void* d_ws, size_t ws_size,
                              hipStream_t stream) {
  const float* reward       = (const float*)d_in[0];
  const int*   step_type    = (const int*)  d_in[1];
  const float* discount     = (const float*)d_in[2];
  const float* value        = (const float*)d_in[3];
  const float* target_value = (const float*)d_in[4];
  float* out  = (float*)d_out;
  float* rets = (float*)d_ws;   // (T-1)*B*Q floats = 13.0 MB

  // K1: B*Q = 25600 threads = 100 blocks x 256
  scan_kernel<<<100, 256, 0, stream>>>(reward, step_type, discount,
                                       target_value, rets);

  // K2: one wave per (t,b) incl. the zero row: 128*512 waves, 4 waves/block
  const int n_waves  = T_DIM * B_DIM;
  const int n_blocks = n_waves / 4;   // 16384
  loss_kernel<<<n_blocks, 256, 0, stream>>>(value, rets, out);
}